// Round 1
// baseline (1122.532 us; speedup 1.0000x reference)
//
#include <hip/hip_runtime.h>

#define Bn 4
#define Cn 4096
#define Mn 2048
#define Hn 16
#define Dn 128
#define Sn 64

// ---------------------------------------------------------------------------
// Kernel 1: pos[b][h][c] = pos_weight[h]*c + dot(x[b][c][:], W[h][:])
// One wave handles 4 consecutive rows (b,c..c+3) x all 16 heads.
// Lanes split M via float4 (lane l covers float4 indices {j*64+l}, j=0..7).
// Reduction: 2-level shfl_xor (groups of 4 lanes) -> padded LDS transpose.
// ---------------------------------------------------------------------------
__global__ __launch_bounds__(256, 4) void pos_kernel(
    const float* __restrict__ x,    // [B][C][M]
    const float* __restrict__ W,    // [H][M]
    const float* __restrict__ pw,   // [H]
    float* __restrict__ pos)        // [B][H][C]
{
    __shared__ float red[4][64 * 17];   // per-wave: 64 values x 16 group-partials, stride 17 (bank-conflict-free)

    const int wid  = threadIdx.x >> 6;
    const int lane = threadIdx.x & 63;
    const int wave = blockIdx.x * 4 + wid;
    const int row0 = wave * 4;              // global row = b*C + c
    const int b    = row0 >> 12;            // / 4096
    const int c0   = row0 & 4095;

    const float4* x4 = (const float4*)x;
    const float4* W4 = (const float4*)W;
    const size_t xbase = (size_t)row0 * (Mn / 4);

    float acc[4][16];
#pragma unroll
    for (int r = 0; r < 4; ++r)
#pragma unroll
        for (int h = 0; h < Hn; ++h) acc[r][h] = 0.0f;

#pragma unroll
    for (int j = 0; j < 8; ++j) {
        const int m4 = j * 64 + lane;       // float4 index within row
        float4 xv[4];
#pragma unroll
        for (int r = 0; r < 4; ++r)
            xv[r] = x4[xbase + (size_t)r * (Mn / 4) + m4];
#pragma unroll
        for (int h = 0; h < Hn; ++h) {
            const float4 wv = W4[h * (Mn / 4) + m4];
#pragma unroll
            for (int r = 0; r < 4; ++r) {
                acc[r][h] += xv[r].x * wv.x;
                acc[r][h] += xv[r].y * wv.y;
                acc[r][h] += xv[r].z * wv.z;
                acc[r][h] += xv[r].w * wv.w;
            }
        }
    }

    // pre-reduce within groups of 4 consecutive lanes, then stash group partials
    float* rw = &red[wid][0];
    const int g = lane >> 2;
#pragma unroll
    for (int r = 0; r < 4; ++r) {
#pragma unroll
        for (int h = 0; h < Hn; ++h) {
            float v = acc[r][h];
            v += __shfl_xor(v, 1);
            v += __shfl_xor(v, 2);
            if ((lane & 3) == 0) rw[(r * 16 + h) * 17 + g] = v;
        }
    }
    __syncthreads();

    // lane v sums its value's 16 group partials (stride-17 -> conflict-free)
    const int v = lane;
    float s = 0.0f;
#pragma unroll
    for (int gg = 0; gg < 16; ++gg) s += rw[v * 17 + gg];

    const int r = v >> 4;
    const int h = v & 15;
    const int c = c0 + r;
    pos[((size_t)(b * Hn + h)) * Cn + c] = pw[h] * (float)c + s;
}

// ---------------------------------------------------------------------------
// Kernel 2: rotate q and k. One thread per float4 = 2 (p0,p1) pairs.
// angle = pos * theta[s]; sin/cos via revolutions + v_fract + hw v_sin/v_cos.
// ---------------------------------------------------------------------------
__global__ __launch_bounds__(256) void rot_kernel(
    const float* __restrict__ q,
    const float* __restrict__ k,
    const float* __restrict__ theta,   // [S]
    const float* __restrict__ pos,     // [B*H*C]
    float* __restrict__ out)           // [2][B*H*C][D]
{
    const size_t tid = (size_t)blockIdx.x * 256 + threadIdx.x;  // over B*H*C*32
    const int sp = (int)(tid & 31);            // float4 index within row: s pairs 2sp, 2sp+1
    const size_t row = tid >> 5;

    const float p = pos[row];
    const float2 th = ((const float2*)theta)[sp];

    constexpr float inv2pi = 0.15915494309189535f;
    float r0 = p * th.x * inv2pi;
    float r1 = p * th.y * inv2pi;
    r0 = r0 - floorf(r0);                      // fract -> [0,1) revolutions
    r1 = r1 - floorf(r1);
    const float cs0 = __builtin_amdgcn_cosf(r0);
    const float sn0 = __builtin_amdgcn_sinf(r0);
    const float cs1 = __builtin_amdgcn_cosf(r1);
    const float sn1 = __builtin_amdgcn_sinf(r1);

    const float4* q4 = (const float4*)q;
    const float4* k4 = (const float4*)k;
    float4* o4 = (float4*)out;
    const size_t idx = row * 32 + sp;
    const size_t half = (size_t)Bn * Hn * Cn * 32;

    const float4 qv = q4[idx];
    float4 ov;
    ov.x = cs0 * qv.x - sn0 * qv.y;
    ov.y = sn0 * qv.x + cs0 * qv.y;
    ov.z = cs1 * qv.z - sn1 * qv.w;
    ov.w = sn1 * qv.z + cs1 * qv.w;
    o4[idx] = ov;

    const float4 kv = k4[idx];
    ov.x = cs0 * kv.x - sn0 * kv.y;
    ov.y = sn0 * kv.x + cs0 * kv.y;
    ov.z = cs1 * kv.z - sn1 * kv.w;
    ov.w = sn1 * kv.z + cs1 * kv.w;
    o4[idx + half] = ov;
}

extern "C" void kernel_launch(void* const* d_in, const int* in_sizes, int n_in,
                              void* d_out, int out_size, void* d_ws, size_t ws_size,
                              hipStream_t stream) {
    const float* x     = (const float*)d_in[0];  // [B,C,M]
    const float* q     = (const float*)d_in[1];  // [B,H,C,D]
    const float* k     = (const float*)d_in[2];  // [B,H,C,D]
    const float* W     = (const float*)d_in[3];  // [H,M]
    const float* pw    = (const float*)d_in[4];  // [H]
    const float* theta = (const float*)d_in[5];  // [S]
    float* out = (float*)d_out;
    float* pos = (float*)d_ws;                   // B*H*C floats = 1 MB

    // Kernel 1: B*C/4 = 4096 waves -> 1024 blocks of 256
    pos_kernel<<<1024, 256, 0, stream>>>(x, W, pw, pos);

    // Kernel 2: B*H*C*32 threads = 8388608 -> 32768 blocks of 256
    rot_kernel<<<32768, 256, 0, stream>>>(q, k, theta, pos, out);
}